// Round 9
// baseline (237.224 us; speedup 1.0000x reference)
//
#include <hip/hip_runtime.h>
#include <hip/hip_fp16.h>
#include <math.h>

#define N_NODES   50000
#define N_EDGES   800000
#define IN_DIM    128
#define HID       64
#define OUT_DIM   128
#define N_GRAPHS  256
#define MAX_DEG   64      // ELL row stride; P(deg>64) for Binomial(800k,1/50k) ~ 1e-19
#define HALF_N    25000   // src-half split: phase A gathers T[0:25000) = 3.2 MB (L2-resident)
#define PARTS     8       // XCD count; blockIdx%8 -> XCD round-robin heuristic
#define PSIZE     (N_NODES / PARTS)
#define EPB       4096    // edges per build chunk
#define AGG_NPB   32      // nodes per agg block (4 waves x 8 octets)

typedef _Float16 half8 __attribute__((ext_vector_type(8)));
typedef float floatx4 __attribute__((ext_vector_type(4)));
typedef unsigned int uintx4 __attribute__((ext_vector_type(4)));

// ---------------- preprocessing ----------------

// XCD-partitioned dual-cursor ELL build: srcs<HALF_N fill row front (degA),
// srcs>=HALF_N fill row back (degB). Same 64-slot row, collision iff deg>64 (~never).
__global__ __launch_bounds__(256) void k_build(const int* __restrict__ src,
                                               const int* __restrict__ dst,
                                               int* __restrict__ degA, int* __restrict__ degB,
                                               int* __restrict__ col) {
    int p     = blockIdx.x & (PARTS - 1);
    int chunk = blockIdx.x >> 3;
    int base  = chunk * EPB;
    int lo = p * PSIZE, hi = lo + PSIZE;
#pragma unroll
    for (int j = 0; j < EPB / 256; j++) {
        int e = base + j * 256 + threadIdx.x;
        if (e < N_EDGES) {
            int d = dst[e];
            if (d >= lo && d < hi) {
                int s = src[e];
                if (s < HALF_N) {
                    int pos = atomicAdd(&degA[d], 1);
                    if (pos < MAX_DEG) col[d * MAX_DEG + pos] = s;
                } else {
                    int pos = atomicAdd(&degB[d], 1);
                    if (pos < MAX_DEG) col[d * MAX_DEG + (MAX_DEG - 1 - pos)] = s;
                }
            }
        }
    }
}

// merged: dinv (blocks 0..195) + pack W1 (196..199) + pack W2 (200..201)
__global__ __launch_bounds__(256) void k_prep(const int* __restrict__ degA,
                                              const int* __restrict__ degB,
                                              float* __restrict__ dinv,
                                              const float* __restrict__ W1, __half* __restrict__ Wt1,
                                              const float* __restrict__ W2, __half* __restrict__ Wt2) {
    int blk = blockIdx.x;
    if (blk < 196) {
        int n = blk * 256 + threadIdx.x;
        if (n < N_NODES) dinv[n] = rsqrtf((float)(degA[n] + degB[n] + 1));  // +1 self-loop
    } else if (blk < 200) {
        int idx = (blk - 196) * 256 + threadIdx.x;   // (128/8)*64 = 1024
        int g = idx >> 6, n = idx & 63;
#pragma unroll
        for (int i = 0; i < 8; i++)
            Wt1[idx * 8 + i] = __float2half(W1[(8 * g + i) * 64 + n]);
    } else {
        int idx = (blk - 200) * 256 + threadIdx.x;   // (64/8)*64 = 512
        if (idx < 512) {
            int g = idx >> 6, n = idx & 63;
#pragma unroll
            for (int i = 0; i < 8; i++)
                Wt2[idx * 8 + i] = __float2half(W2[(8 * g + i) * 64 + n]);
        }
    }
}

// ---------------- MFMA GEMM layer 1: C = (dinv ⊙ x_fp32) @ W1, cvt fused ----------------

__global__ __launch_bounds__(256) void k_mfma1(const float* __restrict__ A,
                                               const float* __restrict__ dinv,
                                               const __half* __restrict__ Bp,
                                               __half* __restrict__ C) {
    constexpr int K = IN_DIM, S = K / 32;
    int wv   = threadIdx.x >> 6;
    int lane = threadIdx.x & 63;
    int quad = lane >> 4, l15 = lane & 15;
    int row0 = blockIdx.x * 64 + wv * 16;
    if (row0 >= N_NODES) return;   // 50000 % 16 == 0

    half8 bf[S][4];
#pragma unroll
    for (int s = 0; s < S; s++)
#pragma unroll
        for (int j = 0; j < 4; j++)
            bf[s][j] = *(const half8*)(Bp + ((size_t)((4 * s + quad) * 64 + 16 * j + l15)) * 8);

    floatx4 acc[4];
#pragma unroll
    for (int j = 0; j < 4; j++) acc[j] = 0.f;

    int arow = row0 + l15;
    float dv = dinv[arow];
#pragma unroll
    for (int s = 0; s < S; s++) {
        floatx4 xa = __builtin_nontemporal_load((const floatx4*)(A + (size_t)arow * K + 32 * s + quad * 8));
        floatx4 xb = __builtin_nontemporal_load((const floatx4*)(A + (size_t)arow * K + 32 * s + quad * 8 + 4));
        half8 af;
        af[0] = (_Float16)(xa[0] * dv); af[1] = (_Float16)(xa[1] * dv);
        af[2] = (_Float16)(xa[2] * dv); af[3] = (_Float16)(xa[3] * dv);
        af[4] = (_Float16)(xb[0] * dv); af[5] = (_Float16)(xb[1] * dv);
        af[6] = (_Float16)(xb[2] * dv); af[7] = (_Float16)(xb[3] * dv);
#pragma unroll
        for (int j = 0; j < 4; j++)
            acc[j] = __builtin_amdgcn_mfma_f32_16x16x32_f16(af, bf[s][j], acc[j], 0, 0, 0);
    }
#pragma unroll
    for (int j = 0; j < 4; j++)
#pragma unroll
        for (int r = 0; r < 4; r++)
            C[(size_t)(row0 + quad * 4 + r) * 64 + 16 * j + l15] = __float2half(acc[j][r]);
}

// ---------------- MFMA GEMM layer 2: fp16 A ----------------

__global__ __launch_bounds__(256) void k_mfma2(const __half* __restrict__ A,
                                               const __half* __restrict__ Bp,
                                               __half* __restrict__ C) {
    constexpr int K = HID, S = K / 32;
    int wv   = threadIdx.x >> 6;
    int lane = threadIdx.x & 63;
    int quad = lane >> 4, l15 = lane & 15;
    int row0 = blockIdx.x * 64 + wv * 16;
    if (row0 >= N_NODES) return;

    half8 bf[S][4];
#pragma unroll
    for (int s = 0; s < S; s++)
#pragma unroll
        for (int j = 0; j < 4; j++)
            bf[s][j] = *(const half8*)(Bp + ((size_t)((4 * s + quad) * 64 + 16 * j + l15)) * 8);

    floatx4 acc[4];
#pragma unroll
    for (int j = 0; j < 4; j++) acc[j] = 0.f;

    int arow = row0 + l15;
#pragma unroll
    for (int s = 0; s < S; s++) {
        half8 af = *(const half8*)(A + (size_t)arow * K + 32 * s + quad * 8);
#pragma unroll
        for (int j = 0; j < 4; j++)
            acc[j] = __builtin_amdgcn_mfma_f32_16x16x32_f16(af, bf[s][j], acc[j], 0, 0, 0);
    }
#pragma unroll
    for (int j = 0; j < 4; j++)
#pragma unroll
        for (int r = 0; r < 4; r++)
            C[(size_t)(row0 + quad * 4 + r) * 64 + 16 * j + l15] = __float2half(acc[j][r]);
}

// ---------------- aggregation v4: LDS-staged ELL, src-half phase split ----------------
// Phase A gathers only T[0:HALF_N) (3.2 MB, L2-resident), phase B only T[HALF_N:).
// mode 0: OUT = dinv * gelu_tanh( dinv*(Σ_in T[s] + T[d]) + b ); mode 1: no activation.

__device__ __forceinline__ void add8(float* acc, uintx4 v) {
    const __half2* h = (const __half2*)&v;
#pragma unroll
    for (int j = 0; j < 4; j++) {
        acc[2 * j]     += __low2float(h[j]);
        acc[2 * j + 1] += __high2float(h[j]);
    }
}

__global__ __launch_bounds__(256) void k_agg(const __half* __restrict__ T,
                                             const int* __restrict__ col,
                                             const int* __restrict__ degA,
                                             const int* __restrict__ degB,
                                             const float* __restrict__ dinv,
                                             const float* __restrict__ b,
                                             __half* __restrict__ OUT, int mode) {
    __shared__ int cols[AGG_NPB][MAX_DEG + 1];   // +1 pad: octets in distinct banks
    int base = blockIdx.x * AGG_NPB;

    for (int idx = threadIdx.x; idx < AGG_NPB * MAX_DEG; idx += 256) {
        int r = idx >> 6, j = idx & 63;
        int g = base + r;
        if (g < N_NODES) cols[r][j] = __builtin_nontemporal_load(&col[g * MAX_DEG + j]);
    }
    __syncthreads();

    int lane = threadIdx.x & 63;
    int wv   = threadIdx.x >> 6;
    int q = lane >> 3, t = lane & 7;     // octet = node, t = 16-byte chunk
    int local = wv * 8 + q;
    int d = base + local;
    if (d >= N_NODES) return;

    int dgA = degA[d]; if (dgA > MAX_DEG) dgA = MAX_DEG;
    int dgB = degB[d]; if (dgB > MAX_DEG) dgB = MAX_DEG;

    float acc[8];
#pragma unroll
    for (int j = 0; j < 8; j++) acc[j] = 0.f;
    add8(acc, *(const uintx4*)(T + (size_t)d * HID + t * 8));   // self term

    const int* cl = cols[local];
    // phase A: srcs < HALF_N at slots [0, dgA)
    int i = 0;
    for (; i + 4 <= dgA; i += 4) {
        int s0 = cl[i], s1 = cl[i + 1], s2 = cl[i + 2], s3 = cl[i + 3];
        uintx4 v0 = *(const uintx4*)(T + (size_t)s0 * HID + t * 8);
        uintx4 v1 = *(const uintx4*)(T + (size_t)s1 * HID + t * 8);
        uintx4 v2 = *(const uintx4*)(T + (size_t)s2 * HID + t * 8);
        uintx4 v3 = *(const uintx4*)(T + (size_t)s3 * HID + t * 8);
        add8(acc, v0); add8(acc, v1); add8(acc, v2); add8(acc, v3);
    }
    for (; i < dgA; i++)
        add8(acc, *(const uintx4*)(T + (size_t)cl[i] * HID + t * 8));
    // phase B: srcs >= HALF_N at slots [MAX_DEG-dgB, MAX_DEG), read back-to-front
    i = 0;
    for (; i + 4 <= dgB; i += 4) {
        int s0 = cl[MAX_DEG - 1 - i], s1 = cl[MAX_DEG - 2 - i];
        int s2 = cl[MAX_DEG - 3 - i], s3 = cl[MAX_DEG - 4 - i];
        uintx4 v0 = *(const uintx4*)(T + (size_t)s0 * HID + t * 8);
        uintx4 v1 = *(const uintx4*)(T + (size_t)s1 * HID + t * 8);
        uintx4 v2 = *(const uintx4*)(T + (size_t)s2 * HID + t * 8);
        uintx4 v3 = *(const uintx4*)(T + (size_t)s3 * HID + t * 8);
        add8(acc, v0); add8(acc, v1); add8(acc, v2); add8(acc, v3);
    }
    for (; i < dgB; i++)
        add8(acc, *(const uintx4*)(T + (size_t)cl[MAX_DEG - 1 - i] * HID + t * 8));

    float dv = dinv[d];
    float o[8];
#pragma unroll
    for (int j = 0; j < 8; j++) o[j] = acc[j] * dv;
    if (mode == 0) {
#pragma unroll
        for (int j = 0; j < 8; j++) {
            float v = o[j] + b[t * 8 + j];
            float u2 = 0.7978845608028654f * (v + 0.044715f * v * v * v);
            o[j] = 0.5f * v * (1.0f + tanhf(u2)) * dv;   // pre-scale for next layer
        }
    }
    __half2 hh[4];
#pragma unroll
    for (int j = 0; j < 4; j++) hh[j] = __floats2half2_rn(o[2 * j], o[2 * j + 1]);
    uintx4 st = *(uintx4*)hh;
    __builtin_nontemporal_store(st, (uintx4*)(OUT + (size_t)d * HID + t * 8));
}

// ---------------- fused segmented mean-pool + final GEMM (batch is SORTED) ----------------

__global__ __launch_bounds__(256) void k_pool_out(const __half* __restrict__ A,
                                                  const int* __restrict__ batch,
                                                  const float* __restrict__ W3,
                                                  const float* __restrict__ b3,
                                                  float* __restrict__ out) {
    int g = blockIdx.x;
    int lo = 0, hi = N_NODES;
    while (lo < hi) { int m = (lo + hi) >> 1; if (batch[m] < g) lo = m + 1; else hi = m; }
    int lo2 = lo, hi2 = N_NODES;
    while (lo2 < hi2) { int m = (lo2 + hi2) >> 1; if (batch[m] < g + 1) lo2 = m + 1; else hi2 = m; }
    int start = lo, end = lo2;

    int lane = threadIdx.x & 63;
    int wave = threadIdx.x >> 6;
    float acc = 0.f;
    for (int n = start + wave; n < end; n += 4)
        acc += __half2float(A[(size_t)n * HID + lane]);

    __shared__ float part[4][HID];
    __shared__ float pooled[HID];
    part[wave][lane] = acc;
    __syncthreads();
    if (threadIdx.x < HID)
        pooled[threadIdx.x] = part[0][threadIdx.x] + part[1][threadIdx.x] +
                              part[2][threadIdx.x] + part[3][threadIdx.x];
    __syncthreads();

    if (threadIdx.x < OUT_DIM) {
        float cntf = (float)(end - start);
        float inv = 1.0f / fmaxf(cntf, 1.0f);
        float s = 0.f;
#pragma unroll
        for (int k = 0; k < HID; k++) s += pooled[k] * W3[k * OUT_DIM + threadIdx.x];
        out[g * OUT_DIM + threadIdx.x] = (s + cntf * b3[threadIdx.x]) * inv;
    }
}

// ---------------- launch ----------------

extern "C" void kernel_launch(void* const* d_in, const int* in_sizes, int n_in,
                              void* d_out, int out_size, void* d_ws, size_t ws_size,
                              hipStream_t stream) {
    const float* x     = (const float*)d_in[0];
    const int*   ei    = (const int*)d_in[1];
    const int*   batch = (const int*)d_in[2];
    const float* W1    = (const float*)d_in[4];
    const float* b1    = (const float*)d_in[5];
    const float* W2    = (const float*)d_in[6];
    const float* b2    = (const float*)d_in[7];
    const float* W3    = (const float*)d_in[8];
    const float* b3    = (const float*)d_in[9];
    float* out = (float*)d_out;

    const int* esrc = ei;
    const int* edst = ei + N_EDGES;

    // workspace layout (degA+degB = contiguous zero region)
    int*    degA = (int*)d_ws;                           // 50000 (zero)
    int*    degB = degA + N_NODES;                       // 50000 (zero)
    float*  dinv = (float*)(degB + N_NODES);             // 50000
    int*    col  = (int*)(dinv + N_NODES);               // 3.2M ints (12.8 MB)
    __half* t    = (__half*)(col + (size_t)N_NODES * MAX_DEG);   // 3.2M halves
    __half* p    = t + (size_t)N_NODES * HID;                    // 3.2M halves
    __half* Wt1  = p + (size_t)N_NODES * HID;                    // 8192 halves
    __half* Wt2  = Wt1 + IN_DIM * HID;                           // 4096 halves

    (void)hipMemsetAsync(degA, 0, (size_t)(2 * N_NODES) * 4, stream);

    const int CHUNKS = (N_EDGES + EPB - 1) / EPB;        // 196
    k_build<<<CHUNKS * PARTS, 256, 0, stream>>>(esrc, edst, degA, degB, col);
    k_prep<<<202, 256, 0, stream>>>(degA, degB, dinv, W1, Wt1, W2, Wt2);

    const int GB = (N_NODES + 63) / 64;                  // 782 MFMA blocks
    const int AB = (N_NODES + AGG_NPB - 1) / AGG_NPB;    // 1563 agg blocks

    // layer 1 (x-cvt + dinv pre-scale fused into MFMA A-load)
    k_mfma1<<<GB, 256, 0, stream>>>(x, dinv, Wt1, t);
    k_agg<<<AB, 256, 0, stream>>>(t, col, degA, degB, dinv, b1, p, 0);
    // layer 2
    k_mfma2<<<GB, 256, 0, stream>>>(p, Wt2, t);
    k_agg<<<AB, 256, 0, stream>>>(t, col, degA, degB, dinv, b2, p, 0);
    // layer 3 aggregate (width 64, pre-GEMM)
    k_agg<<<AB, 256, 0, stream>>>(p, col, degA, degB, dinv, b3, t, 1);
    // fused mean-pool + 64->128 GEMM
    k_pool_out<<<N_GRAPHS, 256, 0, stream>>>(t, batch, W3, b3, out);
}